// Round 6
// baseline (203.497 us; speedup 1.0000x reference)
//
#include <hip/hip_runtime.h>
#include <math.h>

namespace {

constexpr int B_   = 8;
constexpr int S_   = 8192;
constexpr int NROW = B_ * S_;      // 65536
constexpr int MC   = 48;           // model channels
constexpr int OF   = 88;           // output features
constexpr int KW   = 31;           // window
constexpr int F1   = 229;
constexpr int F2   = 136;          // 88 + 48

typedef __attribute__((ext_vector_type(8))) short bf16x8;
typedef __attribute__((ext_vector_type(4))) float f32x4;

__device__ inline unsigned short f2bf(float v) {
    unsigned u = __float_as_uint(v);
    unsigned r = (u + 0x7FFFu + ((u >> 16) & 1u)) >> 16;
    return (unsigned short)r;
}
__device__ inline float bf2f(unsigned short b) {
    return __uint_as_float((unsigned)b << 16);
}
__device__ inline unsigned pack2(unsigned short a, unsigned short b) {
    return (unsigned)a | ((unsigned)b << 16);
}

// ---- W prep: q,k,v stacked (144 rows) -> bf16 hi/lo, chunk-major -----------
__global__ void wprep_kernel(const float* __restrict__ Wq,
                             const float* __restrict__ Wk,
                             const float* __restrict__ Wv,
                             int K, int nch, unsigned short* __restrict__ out) {
    int idx = blockIdx.x * 256 + threadIdx.x;
    int kpad = nch * 32;
    int total = 144 * kpad;
    if (idx >= total) return;
    int oc = idx / kpad;
    int kg = idx - oc * kpad;
    int c  = kg >> 5, kk = kg & 31;
    float val = 0.f;
    if (kg < K) {
        const float* W = (oc < 48) ? Wq : (oc < 96 ? Wk : Wv);
        int ocl = (oc < 48) ? oc : (oc < 96 ? oc - 48 : oc - 96);
        val = W[ocl * K + kg];
    }
    unsigned short h = f2bf(val);
    unsigned short l = f2bf(val - bf2f(h));
    size_t base = (size_t)c * 16384 + (size_t)oc * 56 + kk;
    out[base]        = h;
    out[base + 8192] = l;
}

// ---- Wo/Wf prep: transpose to [96 n][64 k] bf16, hi plane then lo plane ----
__global__ void woprep_kernel(const float* __restrict__ W,  // [88][48]
                              unsigned short* __restrict__ out) {
    int idx = blockIdx.x * 256 + threadIdx.x;   // 96*64
    if (idx >= 96 * 64) return;
    int n = idx >> 6, k = idx & 63;
    float val = (n < OF && k < MC) ? W[n * MC + k] : 0.f;
    unsigned short h = f2bf(val);
    unsigned short l = f2bf(val - bf2f(h));
    out[idx]        = h;
    out[6144 + idx] = l;
}

// ---- projection GEMM via MFMA, 3-term bf16 hi/lo split (proven) ------------
template<int K, int NCH>
__global__ __launch_bounds__(256) void proj_mfma(
    const float* __restrict__ x,
    const unsigned short* __restrict__ wbuf,
    float* __restrict__ qo, float* __restrict__ ko, float* __restrict__ vo)
{
    __shared__ __attribute__((aligned(16))) unsigned short Ah[64 * 56];
    __shared__ __attribute__((aligned(16))) unsigned short Al[64 * 56];
    __shared__ __attribute__((aligned(16))) unsigned short Bblk[16384];

    const int tid  = threadIdx.x;
    const int row0 = blockIdx.x * 64;
    const int lane = tid & 63;
    const int wm   = tid >> 6;

    f32x4 acc[9];
    #pragma unroll
    for (int nt = 0; nt < 9; ++nt) acc[nt] = f32x4{0.f, 0.f, 0.f, 0.f};

    const int arow = wm * 16 + (lane & 15);
    const int ak   = (lane >> 4) * 8;

    for (int c = 0; c < NCH; ++c) {
        {
            const uint4* src = (const uint4*)(wbuf + (size_t)c * 16384);
            uint4* dst = (uint4*)Bblk;
            #pragma unroll
            for (int i = 0; i < 8; ++i)
                dst[tid + 256 * i] = src[tid + 256 * i];
        }
        const int kc = c * 32;
        #pragma unroll
        for (int i = 0; i < 4; ++i) {
            int idx = tid + 256 * i;
            int r   = idx >> 4;
            int k2  = (idx & 15) * 2;
            int kg  = kc + k2;
            const float* xr = x + (size_t)(row0 + r) * K;
            float v0 = (kg     < K) ? xr[kg]     : 0.f;
            float v1 = (kg + 1 < K) ? xr[kg + 1] : 0.f;
            unsigned short h0 = f2bf(v0), h1 = f2bf(v1);
            unsigned short l0 = f2bf(v0 - bf2f(h0));
            unsigned short l1 = f2bf(v1 - bf2f(h1));
            *(unsigned*)&Ah[r * 56 + k2] = pack2(h0, h1);
            *(unsigned*)&Al[r * 56 + k2] = pack2(l0, l1);
        }
        __syncthreads();

        bf16x8 ah = *(const bf16x8*)&Ah[arow * 56 + ak];
        bf16x8 al = *(const bf16x8*)&Al[arow * 56 + ak];
        #pragma unroll
        for (int nt = 0; nt < 9; ++nt) {
            int bcol = nt * 16 + (lane & 15);
            bf16x8 bh = *(const bf16x8*)&Bblk[bcol * 56 + ak];
            bf16x8 bl = *(const bf16x8*)&Bblk[8192 + bcol * 56 + ak];
            acc[nt] = __builtin_amdgcn_mfma_f32_16x16x32_bf16(ah, bh, acc[nt], 0, 0, 0);
            acc[nt] = __builtin_amdgcn_mfma_f32_16x16x32_bf16(ah, bl, acc[nt], 0, 0, 0);
            acc[nt] = __builtin_amdgcn_mfma_f32_16x16x32_bf16(al, bh, acc[nt], 0, 0, 0);
        }
        __syncthreads();
    }

    const int orow = row0 + wm * 16 + ((lane >> 4) << 2);
    const int ocol = lane & 15;
    #pragma unroll
    for (int nt = 0; nt < 9; ++nt) {
        float* dst = (nt < 3) ? qo : (nt < 6 ? ko : vo);
        int oc = (nt % 3) * 16 + ocol;
        #pragma unroll
        for (int rg = 0; rg < 4; ++rg)
            dst[(size_t)(orow + rg) * MC + oc] = acc[nt][rg];
    }
}

// -------- attention core: softmax + PV + LN only; 64 rows, 512 threads ------
// thread tid = rl*8 + g; y (LN output) written into x2 cols 88..135.
template<bool FIRST>
__global__ __launch_bounds__(512, 8) void attn_core(
    const float* __restrict__ qb,     // [NROW][48]
    const float* __restrict__ kb,
    const float* __restrict__ vb,
    const float* __restrict__ rel,    // [48][31]
    const float* __restrict__ lng,
    const float* __restrict__ lnb,
    float* __restrict__ attn_out,     // [NROW][8][31]   (FIRST only)
    float* __restrict__ x2)           // [NROW][136]: write cols 88..135
{
    __shared__ __attribute__((aligned(16))) float ks[94 * 52];
    __shared__ __attribute__((aligned(16))) float vs[94 * 52];
    __shared__ __attribute__((aligned(16))) float relT[31 * 52];
    __shared__ float lngs[48], lnbs[48];

    const int tid = threadIdx.x;
    const int bid = ((blockIdx.x & 7) << 7) | (blockIdx.x >> 3);  // XCD swizzle (1024%8==0)
    const int bb  = bid >> 7;
    const int st0 = (bid & 127) * 64;
    const size_t base = (size_t)bb * S_;

    // stage k/v halo rows st0-15 .. st0+78 (94 rows x 48 ch, float4)
    for (int idx = tid; idx < 94 * 12; idx += 512) {
        int rr = idx / 12, c4 = idx - rr * 12;
        int si = st0 - 15 + rr;
        float4 k4 = {0.f, 0.f, 0.f, 0.f}, v4 = {0.f, 0.f, 0.f, 0.f};
        if (si >= 0 && si < S_) {
            k4 = *(const float4*)&kb[(base + si) * MC + c4 * 4];
            v4 = *(const float4*)&vb[(base + si) * MC + c4 * 4];
        }
        *(float4*)&ks[rr * 52 + c4 * 4] = k4;
        *(float4*)&vs[rr * 52 + c4 * 4] = v4;
    }
    for (int idx = tid; idx < MC * KW; idx += 512) {
        int c = idx / KW, j = idx - c * KW;
        relT[j * 52 + c] = rel[idx];
    }
    if (tid < 48) { lngs[tid] = lng[tid]; lnbs[tid] = lnb[tid]; }
    __syncthreads();

    const int rl  = tid >> 3;
    const int g   = tid & 7;
    const int ch0 = g * 6;
    const size_t grow = base + st0 + rl;

    const float* qr = qb + grow * MC + ch0;
    float2 q01 = *(const float2*)(qr);
    float2 q23 = *(const float2*)(qr + 2);
    float2 q45 = *(const float2*)(qr + 4);

    float e[KW];
    // q . rel (broadcast reads, init e)
    #pragma unroll
    for (int j = 0; j < KW; ++j) {
        const float* rp = &relT[j * 52 + ch0];
        float2 r01 = *(const float2*)(rp);
        float2 r23 = *(const float2*)(rp + 2);
        float2 r45 = *(const float2*)(rp + 4);
        e[j] = q01.x * r01.x + q01.y * r01.y + q23.x * r23.x
             + q23.y * r23.y + q45.x * r45.x + q45.y * r45.y;
    }
    // + q . k
    float mx = -1e30f;
    #pragma unroll
    for (int j = 0; j < KW; ++j) {
        const float* kp = &ks[(rl + j) * 52 + ch0];
        float2 k01 = *(const float2*)(kp);
        float2 k23 = *(const float2*)(kp + 2);
        float2 k45 = *(const float2*)(kp + 4);
        float s = e[j] + q01.x * k01.x + q01.y * k01.y + q23.x * k23.x
                       + q23.y * k23.y + q45.x * k45.x + q45.y * k45.y;
        e[j] = s;
        mx = fmaxf(mx, s);
    }
    float den = 0.f;
    #pragma unroll
    for (int j = 0; j < KW; ++j) { float t = __expf(e[j] - mx); e[j] = t; den += t; }
    float rden = 1.f / den;

    float o0 = 0.f, o1 = 0.f, o2 = 0.f, o3 = 0.f, o4 = 0.f, o5 = 0.f;
    float* aout = FIRST ? (attn_out + (grow * 8 + g) * KW) : nullptr;
    #pragma unroll
    for (int j = 0; j < KW; ++j) {
        float aw = e[j] * rden;
        if constexpr (FIRST) aout[j] = aw;
        const float* vp = &vs[(rl + j) * 52 + ch0];
        float2 v01 = *(const float2*)(vp);
        float2 v23 = *(const float2*)(vp + 2);
        float2 v45 = *(const float2*)(vp + 4);
        o0 += aw * v01.x; o1 += aw * v01.y; o2 += aw * v23.x;
        o3 += aw * v23.y; o4 += aw * v45.x; o5 += aw * v45.y;
    }

    // LayerNorm across 48 channels (8 g-lanes x 6)
    float sum = o0 + o1 + o2 + o3 + o4 + o5;
    sum += __shfl_xor(sum, 1, 8);
    sum += __shfl_xor(sum, 2, 8);
    sum += __shfl_xor(sum, 4, 8);
    float mu = sum * (1.f / 48.f);
    float d0 = o0 - mu, d1 = o1 - mu, d2 = o2 - mu, d3 = o3 - mu, d4 = o4 - mu, d5 = o5 - mu;
    float vr = d0*d0 + d1*d1 + d2*d2 + d3*d3 + d4*d4 + d5*d5;
    vr += __shfl_xor(vr, 1, 8);
    vr += __shfl_xor(vr, 2, 8);
    vr += __shfl_xor(vr, 4, 8);
    float rstd = rsqrtf(vr * (1.f / 48.f) + 1e-5f);

    float* xp = x2 + grow * F2 + OF + ch0;
    *(float2*)(xp)     = float2{d0 * rstd * lngs[ch0]     + lnbs[ch0],
                                d1 * rstd * lngs[ch0 + 1] + lnbs[ch0 + 1]};
    *(float2*)(xp + 2) = float2{d2 * rstd * lngs[ch0 + 2] + lnbs[ch0 + 2],
                                d3 * rstd * lngs[ch0 + 3] + lnbs[ch0 + 3]};
    *(float2*)(xp + 4) = float2{d4 * rstd * lngs[ch0 + 4] + lnbs[ch0 + 4],
                                d5 * rstd * lngs[ch0 + 5] + lnbs[ch0 + 5]};
}

// -------- pred GEMM: y[64x48] x WoT[48x88] + bias + sigmoid -----------------
// reads y from x2 cols 88..135; writes pred; FIRST also writes x2 cols 0..87.
template<bool FIRST>
__global__ __launch_bounds__(256) void pred_gemm(
    const float* __restrict__ x2,
    const unsigned short* __restrict__ wop,  // [2][96][64] bf16 hi/lo
    const float* __restrict__ bo,
    float* __restrict__ pred,
    float* __restrict__ x2w)
{
    __shared__ __attribute__((aligned(16))) unsigned short yh[64 * 72];
    __shared__ __attribute__((aligned(16))) unsigned short yl[64 * 72];
    __shared__ float bosL[96];

    const int tid  = threadIdx.x;
    const int row0 = blockIdx.x * 64;

    for (int idx = tid; idx < 768; idx += 256) {
        int r = idx / 12, c4 = idx - r * 12;
        float4 v4 = *(const float4*)&x2[(size_t)(row0 + r) * F2 + OF + c4 * 4];
        unsigned short h0 = f2bf(v4.x), h1 = f2bf(v4.y), h2 = f2bf(v4.z), h3 = f2bf(v4.w);
        unsigned short l0 = f2bf(v4.x - bf2f(h0)), l1 = f2bf(v4.y - bf2f(h1));
        unsigned short l2 = f2bf(v4.z - bf2f(h2)), l3 = f2bf(v4.w - bf2f(h3));
        *(uint2*)&yh[r * 72 + c4 * 4] = uint2{pack2(h0, h1), pack2(h2, h3)};
        *(uint2*)&yl[r * 72 + c4 * 4] = uint2{pack2(l0, l1), pack2(l2, l3)};
    }
    for (int idx = tid; idx < 384; idx += 256) {   // zero k=48..71 pad
        int r = idx / 6, u = idx - r * 6;
        *(uint2*)&yh[r * 72 + 48 + u * 4] = uint2{0u, 0u};
        *(uint2*)&yl[r * 72 + 48 + u * 4] = uint2{0u, 0u};
    }
    if (tid < 96) bosL[tid] = (tid < OF) ? bo[tid] : 0.f;
    __syncthreads();

    const int l   = tid & 63;
    const int w   = tid >> 6;
    const int lr  = l & 15;
    const int lk8 = (l >> 4) * 8;

    const int arow = w * 16 + lr;
    bf16x8 ah0 = *(const bf16x8*)&yh[arow * 72 + lk8];
    bf16x8 al0 = *(const bf16x8*)&yl[arow * 72 + lk8];
    bf16x8 ah1 = *(const bf16x8*)&yh[arow * 72 + 32 + lk8];
    bf16x8 al1 = *(const bf16x8*)&yl[arow * 72 + 32 + lk8];

    const int rowo = row0 + w * 16 + ((l >> 4) << 2);
    #pragma unroll
    for (int nt = 0; nt < 6; ++nt) {
        int ncol = nt * 16 + lr;
        bf16x8 bh0 = *(const bf16x8*)&wop[(size_t)ncol * 64 + lk8];
        bf16x8 bl0 = *(const bf16x8*)&wop[6144 + (size_t)ncol * 64 + lk8];
        bf16x8 bh1 = *(const bf16x8*)&wop[(size_t)ncol * 64 + 32 + lk8];
        bf16x8 bl1 = *(const bf16x8*)&wop[6144 + (size_t)ncol * 64 + 32 + lk8];
        f32x4 oacc = f32x4{0.f, 0.f, 0.f, 0.f};
        oacc = __builtin_amdgcn_mfma_f32_16x16x32_bf16(ah0, bh0, oacc, 0, 0, 0);
        oacc = __builtin_amdgcn_mfma_f32_16x16x32_bf16(ah0, bl0, oacc, 0, 0, 0);
        oacc = __builtin_amdgcn_mfma_f32_16x16x32_bf16(al0, bh0, oacc, 0, 0, 0);
        oacc = __builtin_amdgcn_mfma_f32_16x16x32_bf16(ah1, bh1, oacc, 0, 0, 0);
        oacc = __builtin_amdgcn_mfma_f32_16x16x32_bf16(ah1, bl1, oacc, 0, 0, 0);
        oacc = __builtin_amdgcn_mfma_f32_16x16x32_bf16(al1, bh1, oacc, 0, 0, 0);
        if (ncol < OF) {
            float bias = bosL[ncol];
            #pragma unroll
            for (int rg = 0; rg < 4; ++rg) {
                float s  = oacc[rg] + bias;
                float sg = 1.f / (1.f + __expf(-s));
                size_t row = (size_t)(rowo + rg);
                pred[row * OF + ncol] = sg;
                if constexpr (FIRST) x2w[row * F2 + ncol] = sg;
            }
        }
    }
}

} // namespace

extern "C" void kernel_launch(void* const* d_in, const int* in_sizes, int n_in,
                              void* d_out, int out_size, void* d_ws, size_t ws_size,
                              hipStream_t stream) {
    const float* spec = (const float*)d_in[0];
    const float* Wq1  = (const float*)d_in[1];
    const float* Wk1  = (const float*)d_in[2];
    const float* Wv1  = (const float*)d_in[3];
    const float* rel1 = (const float*)d_in[4];
    const float* ln1g = (const float*)d_in[5];
    const float* ln1b = (const float*)d_in[6];
    const float* Wo   = (const float*)d_in[7];
    const float* bo   = (const float*)d_in[8];
    const float* Wq2  = (const float*)d_in[9];
    const float* Wk2  = (const float*)d_in[10];
    const float* Wv2  = (const float*)d_in[11];
    const float* rel2 = (const float*)d_in[12];
    const float* ln2g = (const float*)d_in[13];
    const float* ln2b = (const float*)d_in[14];
    const float* Wf   = (const float*)d_in[15];
    const float* bf_  = (const float*)d_in[16];

    float* outf   = (float*)d_out;
    float* frame  = outf;
    float* onset  = outf + (size_t)NROW * OF;
    float* attn_a = outf + (size_t)2 * NROW * OF;

    float* wsf = (float*)d_ws;
    float* q1 = wsf;
    float* k1 = q1 + (size_t)NROW * MC;
    float* v1 = k1 + (size_t)NROW * MC;
    float* x2 = v1 + (size_t)NROW * MC;                 // [NROW][136]
    unsigned short* wbuf1 = (unsigned short*)(x2 + (size_t)NROW * F2);
    unsigned short* wbuf2 = wbuf1 + (size_t)8 * 16384;
    unsigned short* woP1  = wbuf2 + (size_t)5 * 16384;  // [2][96][64]
    unsigned short* woP2  = woP1 + 2 * 6144;

    wprep_kernel<<<(144 * 8 * 32 + 255) / 256, 256, 0, stream>>>(Wq1, Wk1, Wv1, F1, 8, wbuf1);
    wprep_kernel<<<(144 * 5 * 32 + 255) / 256, 256, 0, stream>>>(Wq2, Wk2, Wv2, F2, 5, wbuf2);
    woprep_kernel<<<24, 256, 0, stream>>>(Wo, woP1);
    woprep_kernel<<<24, 256, 0, stream>>>(Wf, woP2);

    // phase 1
    proj_mfma<F1, 8><<<NROW / 64, 256, 0, stream>>>(spec, wbuf1, q1, k1, v1);
    attn_core<true><<<NROW / 64, 512, 0, stream>>>(q1, k1, v1, rel1, ln1g, ln1b,
                                                   attn_a, x2);
    pred_gemm<true><<<NROW / 64, 256, 0, stream>>>(x2, woP1, bo, onset, x2);
    // phase 2 (x2 cols 88..135 reused as y scratch)
    proj_mfma<F2, 5><<<NROW / 64, 256, 0, stream>>>(x2, wbuf2, q1, k1, v1);
    attn_core<false><<<NROW / 64, 512, 0, stream>>>(q1, k1, v1, rel2, ln2g, ln2b,
                                                    nullptr, x2);
    pred_gemm<false><<<NROW / 64, 256, 0, stream>>>(x2, woP2, bf_, frame, nullptr);
}

// Round 7
// 202.364 us; speedup vs baseline: 1.0056x; 1.0056x over previous
//
#include <hip/hip_runtime.h>
#include <math.h>

namespace {

constexpr int B_   = 8;
constexpr int S_   = 8192;
constexpr int NROW = B_ * S_;      // 65536
constexpr int MC   = 48;           // model channels
constexpr int OF   = 88;           // output features
constexpr int KW   = 31;           // window
constexpr int F1   = 229;
constexpr int F2   = 136;          // 88 + 48

typedef __attribute__((ext_vector_type(8))) short bf16x8;
typedef __attribute__((ext_vector_type(4))) float f32x4;

__device__ inline unsigned short f2bf(float v) {
    unsigned u = __float_as_uint(v);
    unsigned r = (u + 0x7FFFu + ((u >> 16) & 1u)) >> 16;
    return (unsigned short)r;
}
__device__ inline float bf2f(unsigned short b) {
    return __uint_as_float((unsigned)b << 16);
}
__device__ inline unsigned pack2(unsigned short a, unsigned short b) {
    return (unsigned)a | ((unsigned)b << 16);
}

// ---- W prep: q,k,v stacked (144 rows) -> bf16 hi/lo, chunk-major -----------
__global__ void wprep_kernel(const float* __restrict__ Wq,
                             const float* __restrict__ Wk,
                             const float* __restrict__ Wv,
                             int K, int nch, unsigned short* __restrict__ out) {
    int idx = blockIdx.x * 256 + threadIdx.x;
    int kpad = nch * 32;
    int total = 144 * kpad;
    if (idx >= total) return;
    int oc = idx / kpad;
    int kg = idx - oc * kpad;
    int c  = kg >> 5, kk = kg & 31;
    float val = 0.f;
    if (kg < K) {
        const float* W = (oc < 48) ? Wq : (oc < 96 ? Wk : Wv);
        int ocl = (oc < 48) ? oc : (oc < 96 ? oc - 48 : oc - 96);
        val = W[ocl * K + kg];
    }
    unsigned short h = f2bf(val);
    unsigned short l = f2bf(val - bf2f(h));
    size_t base = (size_t)c * 16384 + (size_t)oc * 56 + kk;
    out[base]        = h;
    out[base + 8192] = l;
}

// ---- Wo/Wf prep: transpose to [96 n][64 k] bf16, hi plane then lo plane ----
__global__ void woprep_kernel(const float* __restrict__ W,  // [88][48]
                              unsigned short* __restrict__ out) {
    int idx = blockIdx.x * 256 + threadIdx.x;   // 96*64
    if (idx >= 96 * 64) return;
    int n = idx >> 6, k = idx & 63;
    float val = (n < OF && k < MC) ? W[n * MC + k] : 0.f;
    unsigned short h = f2bf(val);
    unsigned short l = f2bf(val - bf2f(h));
    out[idx]        = h;
    out[6144 + idx] = l;
}

// ---- projection GEMM via MFMA, 3-term bf16 hi/lo split ---------------------
// Explicit group-of-3 fragment batching + VGPR cap to pin a pipelined schedule
// (round-6 lesson: unconstrained regalloc chose a 68-VGPR serial schedule, 10x slower).
template<int K, int NCH>
__global__ __launch_bounds__(256, 4) void proj_mfma(
    const float* __restrict__ x,
    const unsigned short* __restrict__ wbuf,
    float* __restrict__ qo, float* __restrict__ ko, float* __restrict__ vo)
{
    __shared__ __attribute__((aligned(16))) unsigned short Ah[64 * 56];
    __shared__ __attribute__((aligned(16))) unsigned short Al[64 * 56];
    __shared__ __attribute__((aligned(16))) unsigned short Bblk[16384];

    const int tid  = threadIdx.x;
    const int row0 = blockIdx.x * 64;
    const int lane = tid & 63;
    const int wm   = tid >> 6;
    const int lr   = lane & 15;
    const int ak   = (lane >> 4) * 8;
    const int arow = wm * 16 + lr;

    f32x4 acc[9];
    #pragma unroll
    for (int nt = 0; nt < 9; ++nt) acc[nt] = f32x4{0.f, 0.f, 0.f, 0.f};

    for (int c = 0; c < NCH; ++c) {
        {   // stage W chunk (32 KB)
            const uint4* src = (const uint4*)(wbuf + (size_t)c * 16384);
            uint4* dst = (uint4*)Bblk;
            #pragma unroll
            for (int i = 0; i < 8; ++i)
                dst[tid + 256 * i] = src[tid + 256 * i];
        }
        // stage x chunk: 64 rows x 32 k -> bf16 hi/lo
        const int kc = c * 32;
        #pragma unroll
        for (int i = 0; i < 4; ++i) {
            int idx = tid + 256 * i;
            int r   = idx >> 4;
            int k2  = (idx & 15) * 2;
            int kg  = kc + k2;
            const float* xr = x + (size_t)(row0 + r) * K;
            float v0 = (kg     < K) ? xr[kg]     : 0.f;
            float v1 = (kg + 1 < K) ? xr[kg + 1] : 0.f;
            unsigned short h0 = f2bf(v0), h1 = f2bf(v1);
            unsigned short l0 = f2bf(v0 - bf2f(h0));
            unsigned short l1 = f2bf(v1 - bf2f(h1));
            *(unsigned*)&Ah[r * 56 + k2] = pack2(h0, h1);
            *(unsigned*)&Al[r * 56 + k2] = pack2(l0, l1);
        }
        __syncthreads();

        bf16x8 ah = *(const bf16x8*)&Ah[arow * 56 + ak];
        bf16x8 al = *(const bf16x8*)&Al[arow * 56 + ak];
        #pragma unroll
        for (int grp = 0; grp < 3; ++grp) {
            // batched loads: 6 ds_read_b128 issued together
            bf16x8 bh0 = *(const bf16x8*)&Bblk[((grp * 3 + 0) * 16 + lr) * 56 + ak];
            bf16x8 bl0 = *(const bf16x8*)&Bblk[8192 + ((grp * 3 + 0) * 16 + lr) * 56 + ak];
            bf16x8 bh1 = *(const bf16x8*)&Bblk[((grp * 3 + 1) * 16 + lr) * 56 + ak];
            bf16x8 bl1 = *(const bf16x8*)&Bblk[8192 + ((grp * 3 + 1) * 16 + lr) * 56 + ak];
            bf16x8 bh2 = *(const bf16x8*)&Bblk[((grp * 3 + 2) * 16 + lr) * 56 + ak];
            bf16x8 bl2 = *(const bf16x8*)&Bblk[8192 + ((grp * 3 + 2) * 16 + lr) * 56 + ak];
            // 9 MFMAs on the batch
            acc[grp * 3 + 0] = __builtin_amdgcn_mfma_f32_16x16x32_bf16(ah, bh0, acc[grp * 3 + 0], 0, 0, 0);
            acc[grp * 3 + 0] = __builtin_amdgcn_mfma_f32_16x16x32_bf16(ah, bl0, acc[grp * 3 + 0], 0, 0, 0);
            acc[grp * 3 + 0] = __builtin_amdgcn_mfma_f32_16x16x32_bf16(al, bh0, acc[grp * 3 + 0], 0, 0, 0);
            acc[grp * 3 + 1] = __builtin_amdgcn_mfma_f32_16x16x32_bf16(ah, bh1, acc[grp * 3 + 1], 0, 0, 0);
            acc[grp * 3 + 1] = __builtin_amdgcn_mfma_f32_16x16x32_bf16(ah, bl1, acc[grp * 3 + 1], 0, 0, 0);
            acc[grp * 3 + 1] = __builtin_amdgcn_mfma_f32_16x16x32_bf16(al, bh1, acc[grp * 3 + 1], 0, 0, 0);
            acc[grp * 3 + 2] = __builtin_amdgcn_mfma_f32_16x16x32_bf16(ah, bh2, acc[grp * 3 + 2], 0, 0, 0);
            acc[grp * 3 + 2] = __builtin_amdgcn_mfma_f32_16x16x32_bf16(ah, bl2, acc[grp * 3 + 2], 0, 0, 0);
            acc[grp * 3 + 2] = __builtin_amdgcn_mfma_f32_16x16x32_bf16(al, bh2, acc[grp * 3 + 2], 0, 0, 0);
        }
        __syncthreads();
    }

    const int orow = row0 + wm * 16 + ((lane >> 4) << 2);
    #pragma unroll
    for (int nt = 0; nt < 9; ++nt) {
        float* dst = (nt < 3) ? qo : (nt < 6 ? ko : vo);
        int oc = (nt % 3) * 16 + lr;
        #pragma unroll
        for (int rg = 0; rg < 4; ++rg)
            dst[(size_t)(orow + rg) * MC + oc] = acc[nt][rg];
    }
}

// -------- attention core: softmax + PV + LN only; 64 rows, 512 threads ------
// thread tid = rl*8 + g; y (LN output) written into x2 cols 88..135.
template<bool FIRST>
__global__ __launch_bounds__(512, 6) void attn_core(
    const float* __restrict__ qb,     // [NROW][48]
    const float* __restrict__ kb,
    const float* __restrict__ vb,
    const float* __restrict__ rel,    // [48][31]
    const float* __restrict__ lng,
    const float* __restrict__ lnb,
    float* __restrict__ attn_out,     // [NROW][8][31]   (FIRST only)
    float* __restrict__ x2)           // [NROW][136]: write cols 88..135
{
    __shared__ __attribute__((aligned(16))) float ks[94 * 52];
    __shared__ __attribute__((aligned(16))) float vs[94 * 52];
    __shared__ __attribute__((aligned(16))) float relT[31 * 52];
    __shared__ float lngs[48], lnbs[48];

    const int tid = threadIdx.x;
    const int bid = ((blockIdx.x & 7) << 7) | (blockIdx.x >> 3);  // XCD swizzle (1024%8==0)
    const int bb  = bid >> 7;
    const int st0 = (bid & 127) * 64;
    const size_t base = (size_t)bb * S_;

    for (int idx = tid; idx < 94 * 12; idx += 512) {
        int rr = idx / 12, c4 = idx - rr * 12;
        int si = st0 - 15 + rr;
        float4 k4 = {0.f, 0.f, 0.f, 0.f}, v4 = {0.f, 0.f, 0.f, 0.f};
        if (si >= 0 && si < S_) {
            k4 = *(const float4*)&kb[(base + si) * MC + c4 * 4];
            v4 = *(const float4*)&vb[(base + si) * MC + c4 * 4];
        }
        *(float4*)&ks[rr * 52 + c4 * 4] = k4;
        *(float4*)&vs[rr * 52 + c4 * 4] = v4;
    }
    for (int idx = tid; idx < MC * KW; idx += 512) {
        int c = idx / KW, j = idx - c * KW;
        relT[j * 52 + c] = rel[idx];
    }
    if (tid < 48) { lngs[tid] = lng[tid]; lnbs[tid] = lnb[tid]; }
    __syncthreads();

    const int rl  = tid >> 3;
    const int g   = tid & 7;
    const int ch0 = g * 6;
    const size_t grow = base + st0 + rl;

    const float* qr = qb + grow * MC + ch0;
    float2 q01 = *(const float2*)(qr);
    float2 q23 = *(const float2*)(qr + 2);
    float2 q45 = *(const float2*)(qr + 4);

    float e[KW];
    #pragma unroll
    for (int j = 0; j < KW; ++j) {
        const float* rp = &relT[j * 52 + ch0];
        float2 r01 = *(const float2*)(rp);
        float2 r23 = *(const float2*)(rp + 2);
        float2 r45 = *(const float2*)(rp + 4);
        e[j] = q01.x * r01.x + q01.y * r01.y + q23.x * r23.x
             + q23.y * r23.y + q45.x * r45.x + q45.y * r45.y;
    }
    float mx = -1e30f;
    #pragma unroll
    for (int j = 0; j < KW; ++j) {
        const float* kp = &ks[(rl + j) * 52 + ch0];
        float2 k01 = *(const float2*)(kp);
        float2 k23 = *(const float2*)(kp + 2);
        float2 k45 = *(const float2*)(kp + 4);
        float s = e[j] + q01.x * k01.x + q01.y * k01.y + q23.x * k23.x
                       + q23.y * k23.y + q45.x * k45.x + q45.y * k45.y;
        e[j] = s;
        mx = fmaxf(mx, s);
    }
    float den = 0.f;
    #pragma unroll
    for (int j = 0; j < KW; ++j) { float t = __expf(e[j] - mx); e[j] = t; den += t; }
    float rden = 1.f / den;

    float o0 = 0.f, o1 = 0.f, o2 = 0.f, o3 = 0.f, o4 = 0.f, o5 = 0.f;
    float* aout = FIRST ? (attn_out + (grow * 8 + g) * KW) : nullptr;
    #pragma unroll
    for (int j = 0; j < KW; ++j) {
        float aw = e[j] * rden;
        if constexpr (FIRST) aout[j] = aw;
        const float* vp = &vs[(rl + j) * 52 + ch0];
        float2 v01 = *(const float2*)(vp);
        float2 v23 = *(const float2*)(vp + 2);
        float2 v45 = *(const float2*)(vp + 4);
        o0 += aw * v01.x; o1 += aw * v01.y; o2 += aw * v23.x;
        o3 += aw * v23.y; o4 += aw * v45.x; o5 += aw * v45.y;
    }

    float sum = o0 + o1 + o2 + o3 + o4 + o5;
    sum += __shfl_xor(sum, 1, 8);
    sum += __shfl_xor(sum, 2, 8);
    sum += __shfl_xor(sum, 4, 8);
    float mu = sum * (1.f / 48.f);
    float d0 = o0 - mu, d1 = o1 - mu, d2 = o2 - mu, d3 = o3 - mu, d4 = o4 - mu, d5 = o5 - mu;
    float vr = d0*d0 + d1*d1 + d2*d2 + d3*d3 + d4*d4 + d5*d5;
    vr += __shfl_xor(vr, 1, 8);
    vr += __shfl_xor(vr, 2, 8);
    vr += __shfl_xor(vr, 4, 8);
    float rstd = rsqrtf(vr * (1.f / 48.f) + 1e-5f);

    float* xp = x2 + grow * F2 + OF + ch0;
    *(float2*)(xp)     = float2{d0 * rstd * lngs[ch0]     + lnbs[ch0],
                                d1 * rstd * lngs[ch0 + 1] + lnbs[ch0 + 1]};
    *(float2*)(xp + 2) = float2{d2 * rstd * lngs[ch0 + 2] + lnbs[ch0 + 2],
                                d3 * rstd * lngs[ch0 + 3] + lnbs[ch0 + 3]};
    *(float2*)(xp + 4) = float2{d4 * rstd * lngs[ch0 + 4] + lnbs[ch0 + 4],
                                d5 * rstd * lngs[ch0 + 5] + lnbs[ch0 + 5]};
}

// -------- pred GEMM: y[64x48] x WoT[48x88] + bias + sigmoid -----------------
template<bool FIRST>
__global__ __launch_bounds__(256, 4) void pred_gemm(
    const float* x2,                          // note: may alias x2w (disjoint cols)
    const unsigned short* __restrict__ wop,   // [2][96][64] bf16 hi/lo
    const float* __restrict__ bo,
    float* __restrict__ pred,
    float* x2w)
{
    __shared__ __attribute__((aligned(16))) unsigned short yh[64 * 72];
    __shared__ __attribute__((aligned(16))) unsigned short yl[64 * 72];
    __shared__ float bosL[96];

    const int tid  = threadIdx.x;
    const int row0 = blockIdx.x * 64;

    for (int idx = tid; idx < 768; idx += 256) {
        int r = idx / 12, c4 = idx - r * 12;
        float4 v4 = *(const float4*)&x2[(size_t)(row0 + r) * F2 + OF + c4 * 4];
        unsigned short h0 = f2bf(v4.x), h1 = f2bf(v4.y), h2 = f2bf(v4.z), h3 = f2bf(v4.w);
        unsigned short l0 = f2bf(v4.x - bf2f(h0)), l1 = f2bf(v4.y - bf2f(h1));
        unsigned short l2 = f2bf(v4.z - bf2f(h2)), l3 = f2bf(v4.w - bf2f(h3));
        *(uint2*)&yh[r * 72 + c4 * 4] = uint2{pack2(h0, h1), pack2(h2, h3)};
        *(uint2*)&yl[r * 72 + c4 * 4] = uint2{pack2(l0, l1), pack2(l2, l3)};
    }
    for (int idx = tid; idx < 384; idx += 256) {
        int r = idx / 6, u = idx - r * 6;
        *(uint2*)&yh[r * 72 + 48 + u * 4] = uint2{0u, 0u};
        *(uint2*)&yl[r * 72 + 48 + u * 4] = uint2{0u, 0u};
    }
    if (tid < 96) bosL[tid] = (tid < OF) ? bo[tid] : 0.f;
    __syncthreads();

    const int l   = tid & 63;
    const int w   = tid >> 6;
    const int lr  = l & 15;
    const int lk8 = (l >> 4) * 8;

    const int arow = w * 16 + lr;
    bf16x8 ah0 = *(const bf16x8*)&yh[arow * 72 + lk8];
    bf16x8 al0 = *(const bf16x8*)&yl[arow * 72 + lk8];
    bf16x8 ah1 = *(const bf16x8*)&yh[arow * 72 + 32 + lk8];
    bf16x8 al1 = *(const bf16x8*)&yl[arow * 72 + 32 + lk8];

    const int rowo = row0 + w * 16 + ((l >> 4) << 2);
    #pragma unroll
    for (int nt = 0; nt < 6; ++nt) {
        int ncol = nt * 16 + lr;
        bf16x8 bh0 = *(const bf16x8*)&wop[(size_t)ncol * 64 + lk8];
        bf16x8 bl0 = *(const bf16x8*)&wop[6144 + (size_t)ncol * 64 + lk8];
        bf16x8 bh1 = *(const bf16x8*)&wop[(size_t)ncol * 64 + 32 + lk8];
        bf16x8 bl1 = *(const bf16x8*)&wop[6144 + (size_t)ncol * 64 + 32 + lk8];
        f32x4 oacc = f32x4{0.f, 0.f, 0.f, 0.f};
        oacc = __builtin_amdgcn_mfma_f32_16x16x32_bf16(ah0, bh0, oacc, 0, 0, 0);
        oacc = __builtin_amdgcn_mfma_f32_16x16x32_bf16(ah0, bl0, oacc, 0, 0, 0);
        oacc = __builtin_amdgcn_mfma_f32_16x16x32_bf16(al0, bh0, oacc, 0, 0, 0);
        oacc = __builtin_amdgcn_mfma_f32_16x16x32_bf16(ah1, bh1, oacc, 0, 0, 0);
        oacc = __builtin_amdgcn_mfma_f32_16x16x32_bf16(ah1, bl1, oacc, 0, 0, 0);
        oacc = __builtin_amdgcn_mfma_f32_16x16x32_bf16(al1, bh1, oacc, 0, 0, 0);
        if (ncol < OF) {
            float bias = bosL[ncol];
            #pragma unroll
            for (int rg = 0; rg < 4; ++rg) {
                float s  = oacc[rg] + bias;
                float sg = 1.f / (1.f + __expf(-s));
                size_t row = (size_t)(rowo + rg);
                pred[row * OF + ncol] = sg;
                if constexpr (FIRST) x2w[row * F2 + ncol] = sg;
            }
        }
    }
}

} // namespace

extern "C" void kernel_launch(void* const* d_in, const int* in_sizes, int n_in,
                              void* d_out, int out_size, void* d_ws, size_t ws_size,
                              hipStream_t stream) {
    const float* spec = (const float*)d_in[0];
    const float* Wq1  = (const float*)d_in[1];
    const float* Wk1  = (const float*)d_in[2];
    const float* Wv1  = (const float*)d_in[3];
    const float* rel1 = (const float*)d_in[4];
    const float* ln1g = (const float*)d_in[5];
    const float* ln1b = (const float*)d_in[6];
    const float* Wo   = (const float*)d_in[7];
    const float* bo   = (const float*)d_in[8];
    const float* Wq2  = (const float*)d_in[9];
    const float* Wk2  = (const float*)d_in[10];
    const float* Wv2  = (const float*)d_in[11];
    const float* rel2 = (const float*)d_in[12];
    const float* ln2g = (const float*)d_in[13];
    const float* ln2b = (const float*)d_in[14];
    const float* Wf   = (const float*)d_in[15];
    const float* bf_  = (const float*)d_in[16];

    float* outf   = (float*)d_out;
    float* frame  = outf;
    float* onset  = outf + (size_t)NROW * OF;
    float* attn_a = outf + (size_t)2 * NROW * OF;

    float* wsf = (float*)d_ws;
    float* q1 = wsf;
    float* k1 = q1 + (size_t)NROW * MC;
    float* v1 = k1 + (size_t)NROW * MC;
    float* x2 = v1 + (size_t)NROW * MC;                 // [NROW][136]
    unsigned short* wbuf1 = (unsigned short*)(x2 + (size_t)NROW * F2);
    unsigned short* wbuf2 = wbuf1 + (size_t)8 * 16384;
    unsigned short* woP1  = wbuf2 + (size_t)5 * 16384;  // [2][96][64]
    unsigned short* woP2  = woP1 + 2 * 6144;

    wprep_kernel<<<(144 * 8 * 32 + 255) / 256, 256, 0, stream>>>(Wq1, Wk1, Wv1, F1, 8, wbuf1);
    wprep_kernel<<<(144 * 5 * 32 + 255) / 256, 256, 0, stream>>>(Wq2, Wk2, Wv2, F2, 5, wbuf2);
    woprep_kernel<<<24, 256, 0, stream>>>(Wo, woP1);
    woprep_kernel<<<24, 256, 0, stream>>>(Wf, woP2);

    // phase 1
    proj_mfma<F1, 8><<<NROW / 64, 256, 0, stream>>>(spec, wbuf1, q1, k1, v1);
    attn_core<true><<<NROW / 64, 512, 0, stream>>>(q1, k1, v1, rel1, ln1g, ln1b,
                                                   attn_a, x2);
    pred_gemm<true><<<NROW / 64, 256, 0, stream>>>(x2, woP1, bo, onset, x2);
    // phase 2 (x2 cols 88..135 reused as y scratch)
    proj_mfma<F2, 5><<<NROW / 64, 256, 0, stream>>>(x2, wbuf2, q1, k1, v1);
    attn_core<false><<<NROW / 64, 512, 0, stream>>>(q1, k1, v1, rel2, ln2g, ln2b,
                                                    nullptr, x2);
    pred_gemm<false><<<NROW / 64, 256, 0, stream>>>(x2, woP2, bf_, frame, nullptr);
}

// Round 8
// 192.513 us; speedup vs baseline: 1.0571x; 1.0512x over previous
//
#include <hip/hip_runtime.h>
#include <math.h>

namespace {

constexpr int B_   = 8;
constexpr int S_   = 8192;
constexpr int NROW = B_ * S_;      // 65536
constexpr int MC   = 48;           // model channels
constexpr int OF   = 88;           // output features
constexpr int KW   = 31;           // window
constexpr int F1   = 229;
constexpr int F2   = 136;          // 88 + 48

typedef __attribute__((ext_vector_type(8))) short bf16x8;
typedef __attribute__((ext_vector_type(4))) float f32x4;

__device__ inline unsigned short f2bf(float v) {
    unsigned u = __float_as_uint(v);
    unsigned r = (u + 0x7FFFu + ((u >> 16) & 1u)) >> 16;
    return (unsigned short)r;
}
__device__ inline float bf2f(unsigned short b) {
    return __uint_as_float((unsigned)b << 16);
}
__device__ inline unsigned pack2(unsigned short a, unsigned short b) {
    return (unsigned)a | ((unsigned)b << 16);
}

// ---- W prep: q,k,v stacked (144 oc-rows) -> bf16 hi/lo, FRAGMENT-major -----
// element (chunk c, oc, kk) stored at c*9216 + ((kk>>3)*144 + oc)*8 + (kk&7);
// lo plane at +4608. A wave's B-fragment (16 lanes x 16 B) is contiguous.
__global__ void wprep_kernel(const float* __restrict__ Wq,
                             const float* __restrict__ Wk,
                             const float* __restrict__ Wv,
                             int K, int nch, unsigned short* __restrict__ out) {
    int idx = blockIdx.x * 256 + threadIdx.x;
    int kpad = nch * 32;
    int total = 144 * kpad;
    if (idx >= total) return;
    int oc = idx / kpad;
    int kg = idx - oc * kpad;
    int c  = kg >> 5, kk = kg & 31;
    float val = 0.f;
    if (kg < K) {
        const float* W = (oc < 48) ? Wq : (oc < 96 ? Wk : Wv);
        int ocl = (oc < 48) ? oc : (oc < 96 ? oc - 48 : oc - 96);
        val = W[ocl * K + kg];
    }
    unsigned short h = f2bf(val);
    unsigned short l = f2bf(val - bf2f(h));
    size_t base = (size_t)c * 9216 + (size_t)((kk >> 3) * 144 + oc) * 8 + (kk & 7);
    out[base]        = h;
    out[base + 4608] = l;
}

// ---- Wo/Wf prep: transpose to [96 n][64 k] bf16, hi plane then lo plane ----
__global__ void woprep_kernel(const float* __restrict__ W,  // [88][48]
                              unsigned short* __restrict__ out) {
    int idx = blockIdx.x * 256 + threadIdx.x;   // 96*64
    if (idx >= 96 * 64) return;
    int n = idx >> 6, k = idx & 63;
    float val = (n < OF && k < MC) ? W[n * MC + k] : 0.f;
    unsigned short h = f2bf(val);
    unsigned short l = f2bf(val - bf2f(h));
    out[idx]        = h;
    out[6144 + idx] = l;
}

// ---- projection GEMM via MFMA, 3-term bf16 hi/lo split ---------------------
// Zero-LDS, zero-barrier: B fragments loaded coalesced from L2-resident
// fragment-major wbuf; A loaded per-lane from x and converted in-register.
// (round-6/7 lesson: the LDS+barrier structure let regalloc pick a 68-VGPR
// serial schedule, 8x slower; no barriers + batched loads sidesteps it.)
template<int K, int NCH>
__global__ __launch_bounds__(256, 3) void proj_mfma(
    const float* __restrict__ x,
    const unsigned short* __restrict__ wbuf,
    float* __restrict__ qo, float* __restrict__ ko, float* __restrict__ vo)
{
    const int tid  = threadIdx.x;
    const int row0 = blockIdx.x * 64;
    const int lane = tid & 63;
    const int wm   = tid >> 6;
    const int lr   = lane & 15;
    const int hig  = lane >> 4;          // 0..3
    const int arow = wm * 16 + lr;       // this lane's A row (0..63)

    const float* xrow = x + (size_t)(row0 + arow) * K;
    const unsigned short* wl = wbuf + (size_t)(hig * 144 + lr) * 8;

    f32x4 acc[9];
    #pragma unroll
    for (int nt = 0; nt < 9; ++nt) acc[nt] = f32x4{0.f, 0.f, 0.f, 0.f};

    for (int c = 0; c < NCH; ++c) {
        const int k0 = c * 32 + hig * 8;
        // A: 8 floats of this lane's row (HBM/L3; deepest latency -> issue first)
        float av[8];
        #pragma unroll
        for (int u = 0; u < 8; ++u)
            av[u] = (k0 + u < K) ? xrow[k0 + u] : 0.f;

        // B: 18 coalesced 16-B fragments (L1/L2-resident)
        const unsigned short* wc = wl + (size_t)c * 9216;
        bf16x8 bh[9], bl[9];
        #pragma unroll
        for (int nt = 0; nt < 9; ++nt) {
            bh[nt] = *(const bf16x8*)&wc[nt * 128];
            bl[nt] = *(const bf16x8*)&wc[4608 + nt * 128];
        }
        __builtin_amdgcn_sched_barrier(0);   // keep the load cluster issued up front

        // convert A to hi/lo bf16x8 (waits only on the A loads)
        union { bf16x8 v; unsigned u[4]; } ah, al;
        #pragma unroll
        for (int p = 0; p < 4; ++p) {
            unsigned short h0 = f2bf(av[2 * p]);
            unsigned short h1 = f2bf(av[2 * p + 1]);
            ah.u[p] = pack2(h0, h1);
            al.u[p] = pack2(f2bf(av[2 * p]     - bf2f(h0)),
                            f2bf(av[2 * p + 1] - bf2f(h1)));
        }

        #pragma unroll
        for (int nt = 0; nt < 9; ++nt) {
            acc[nt] = __builtin_amdgcn_mfma_f32_16x16x32_bf16(ah.v, bh[nt], acc[nt], 0, 0, 0);
            acc[nt] = __builtin_amdgcn_mfma_f32_16x16x32_bf16(ah.v, bl[nt], acc[nt], 0, 0, 0);
            acc[nt] = __builtin_amdgcn_mfma_f32_16x16x32_bf16(al.v, bh[nt], acc[nt], 0, 0, 0);
        }
    }

    const int orow = row0 + wm * 16 + (hig << 2);
    #pragma unroll
    for (int nt = 0; nt < 9; ++nt) {
        float* dst = (nt < 3) ? qo : (nt < 6 ? ko : vo);
        int oc = (nt % 3) * 16 + lr;
        #pragma unroll
        for (int rg = 0; rg < 4; ++rg)
            dst[(size_t)(orow + rg) * MC + oc] = acc[nt][rg];
    }
}

// -------- attention core: softmax + PV + LN only; 64 rows, 512 threads ------
// thread tid = rl*8 + g; y (LN output) written into x2 cols 88..135.
template<bool FIRST>
__global__ __launch_bounds__(512, 6) void attn_core(
    const float* __restrict__ qb,     // [NROW][48]
    const float* __restrict__ kb,
    const float* __restrict__ vb,
    const float* __restrict__ rel,    // [48][31]
    const float* __restrict__ lng,
    const float* __restrict__ lnb,
    float* __restrict__ attn_out,     // [NROW][8][31]   (FIRST only)
    float* __restrict__ x2)           // [NROW][136]: write cols 88..135
{
    __shared__ __attribute__((aligned(16))) float ks[94 * 52];
    __shared__ __attribute__((aligned(16))) float vs[94 * 52];
    __shared__ __attribute__((aligned(16))) float relT[31 * 52];
    __shared__ float lngs[48], lnbs[48];

    const int tid = threadIdx.x;
    const int bid = ((blockIdx.x & 7) << 7) | (blockIdx.x >> 3);  // XCD swizzle (1024%8==0)
    const int bb  = bid >> 7;
    const int st0 = (bid & 127) * 64;
    const size_t base = (size_t)bb * S_;

    for (int idx = tid; idx < 94 * 12; idx += 512) {
        int rr = idx / 12, c4 = idx - rr * 12;
        int si = st0 - 15 + rr;
        float4 k4 = {0.f, 0.f, 0.f, 0.f}, v4 = {0.f, 0.f, 0.f, 0.f};
        if (si >= 0 && si < S_) {
            k4 = *(const float4*)&kb[(base + si) * MC + c4 * 4];
            v4 = *(const float4*)&vb[(base + si) * MC + c4 * 4];
        }
        *(float4*)&ks[rr * 52 + c4 * 4] = k4;
        *(float4*)&vs[rr * 52 + c4 * 4] = v4;
    }
    for (int idx = tid; idx < MC * KW; idx += 512) {
        int c = idx / KW, j = idx - c * KW;
        relT[j * 52 + c] = rel[idx];
    }
    if (tid < 48) { lngs[tid] = lng[tid]; lnbs[tid] = lnb[tid]; }
    __syncthreads();

    const int rl  = tid >> 3;
    const int g   = tid & 7;
    const int ch0 = g * 6;
    const size_t grow = base + st0 + rl;

    const float* qr = qb + grow * MC + ch0;
    float2 q01 = *(const float2*)(qr);
    float2 q23 = *(const float2*)(qr + 2);
    float2 q45 = *(const float2*)(qr + 4);

    float e[KW];
    #pragma unroll
    for (int j = 0; j < KW; ++j) {
        const float* rp = &relT[j * 52 + ch0];
        float2 r01 = *(const float2*)(rp);
        float2 r23 = *(const float2*)(rp + 2);
        float2 r45 = *(const float2*)(rp + 4);
        e[j] = q01.x * r01.x + q01.y * r01.y + q23.x * r23.x
             + q23.y * r23.y + q45.x * r45.x + q45.y * r45.y;
    }
    float mx = -1e30f;
    #pragma unroll
    for (int j = 0; j < KW; ++j) {
        const float* kp = &ks[(rl + j) * 52 + ch0];
        float2 k01 = *(const float2*)(kp);
        float2 k23 = *(const float2*)(kp + 2);
        float2 k45 = *(const float2*)(kp + 4);
        float s = e[j] + q01.x * k01.x + q01.y * k01.y + q23.x * k23.x
                       + q23.y * k23.y + q45.x * k45.x + q45.y * k45.y;
        e[j] = s;
        mx = fmaxf(mx, s);
    }
    float den = 0.f;
    #pragma unroll
    for (int j = 0; j < KW; ++j) { float t = __expf(e[j] - mx); e[j] = t; den += t; }
    float rden = 1.f / den;

    float o0 = 0.f, o1 = 0.f, o2 = 0.f, o3 = 0.f, o4 = 0.f, o5 = 0.f;
    float* aout = FIRST ? (attn_out + (grow * 8 + g) * KW) : nullptr;
    #pragma unroll
    for (int j = 0; j < KW; ++j) {
        float aw = e[j] * rden;
        if constexpr (FIRST) aout[j] = aw;
        const float* vp = &vs[(rl + j) * 52 + ch0];
        float2 v01 = *(const float2*)(vp);
        float2 v23 = *(const float2*)(vp + 2);
        float2 v45 = *(const float2*)(vp + 4);
        o0 += aw * v01.x; o1 += aw * v01.y; o2 += aw * v23.x;
        o3 += aw * v23.y; o4 += aw * v45.x; o5 += aw * v45.y;
    }

    float sum = o0 + o1 + o2 + o3 + o4 + o5;
    sum += __shfl_xor(sum, 1, 8);
    sum += __shfl_xor(sum, 2, 8);
    sum += __shfl_xor(sum, 4, 8);
    float mu = sum * (1.f / 48.f);
    float d0 = o0 - mu, d1 = o1 - mu, d2 = o2 - mu, d3 = o3 - mu, d4 = o4 - mu, d5 = o5 - mu;
    float vr = d0*d0 + d1*d1 + d2*d2 + d3*d3 + d4*d4 + d5*d5;
    vr += __shfl_xor(vr, 1, 8);
    vr += __shfl_xor(vr, 2, 8);
    vr += __shfl_xor(vr, 4, 8);
    float rstd = rsqrtf(vr * (1.f / 48.f) + 1e-5f);

    float* xp = x2 + grow * F2 + OF + ch0;
    *(float2*)(xp)     = float2{d0 * rstd * lngs[ch0]     + lnbs[ch0],
                                d1 * rstd * lngs[ch0 + 1] + lnbs[ch0 + 1]};
    *(float2*)(xp + 2) = float2{d2 * rstd * lngs[ch0 + 2] + lnbs[ch0 + 2],
                                d3 * rstd * lngs[ch0 + 3] + lnbs[ch0 + 3]};
    *(float2*)(xp + 4) = float2{d4 * rstd * lngs[ch0 + 4] + lnbs[ch0 + 4],
                                d5 * rstd * lngs[ch0 + 5] + lnbs[ch0 + 5]};
}

// -------- pred GEMM: y[64x48] x WoT[48x88] + bias + sigmoid -----------------
template<bool FIRST>
__global__ __launch_bounds__(256, 4) void pred_gemm(
    const float* x2,                          // note: may alias x2w (disjoint cols)
    const unsigned short* __restrict__ wop,   // [2][96][64] bf16 hi/lo
    const float* __restrict__ bo,
    float* __restrict__ pred,
    float* x2w)
{
    __shared__ __attribute__((aligned(16))) unsigned short yh[64 * 72];
    __shared__ __attribute__((aligned(16))) unsigned short yl[64 * 72];
    __shared__ float bosL[96];

    const int tid  = threadIdx.x;
    const int row0 = blockIdx.x * 64;

    for (int idx = tid; idx < 768; idx += 256) {
        int r = idx / 12, c4 = idx - r * 12;
        float4 v4 = *(const float4*)&x2[(size_t)(row0 + r) * F2 + OF + c4 * 4];
        unsigned short h0 = f2bf(v4.x), h1 = f2bf(v4.y), h2 = f2bf(v4.z), h3 = f2bf(v4.w);
        unsigned short l0 = f2bf(v4.x - bf2f(h0)), l1 = f2bf(v4.y - bf2f(h1));
        unsigned short l2 = f2bf(v4.z - bf2f(h2)), l3 = f2bf(v4.w - bf2f(h3));
        *(uint2*)&yh[r * 72 + c4 * 4] = uint2{pack2(h0, h1), pack2(h2, h3)};
        *(uint2*)&yl[r * 72 + c4 * 4] = uint2{pack2(l0, l1), pack2(l2, l3)};
    }
    for (int idx = tid; idx < 384; idx += 256) {
        int r = idx / 6, u = idx - r * 6;
        *(uint2*)&yh[r * 72 + 48 + u * 4] = uint2{0u, 0u};
        *(uint2*)&yl[r * 72 + 48 + u * 4] = uint2{0u, 0u};
    }
    if (tid < 96) bosL[tid] = (tid < OF) ? bo[tid] : 0.f;
    __syncthreads();

    const int l   = tid & 63;
    const int w   = tid >> 6;
    const int lr  = l & 15;
    const int lk8 = (l >> 4) * 8;

    const int arow = w * 16 + lr;
    bf16x8 ah0 = *(const bf16x8*)&yh[arow * 72 + lk8];
    bf16x8 al0 = *(const bf16x8*)&yl[arow * 72 + lk8];
    bf16x8 ah1 = *(const bf16x8*)&yh[arow * 72 + 32 + lk8];
    bf16x8 al1 = *(const bf16x8*)&yl[arow * 72 + 32 + lk8];

    const int rowo = row0 + w * 16 + ((l >> 4) << 2);
    #pragma unroll
    for (int nt = 0; nt < 6; ++nt) {
        int ncol = nt * 16 + lr;
        bf16x8 bh0 = *(const bf16x8*)&wop[(size_t)ncol * 64 + lk8];
        bf16x8 bl0 = *(const bf16x8*)&wop[6144 + (size_t)ncol * 64 + lk8];
        bf16x8 bh1 = *(const bf16x8*)&wop[(size_t)ncol * 64 + 32 + lk8];
        bf16x8 bl1 = *(const bf16x8*)&wop[6144 + (size_t)ncol * 64 + 32 + lk8];
        f32x4 oacc = f32x4{0.f, 0.f, 0.f, 0.f};
        oacc = __builtin_amdgcn_mfma_f32_16x16x32_bf16(ah0, bh0, oacc, 0, 0, 0);
        oacc = __builtin_amdgcn_mfma_f32_16x16x32_bf16(ah0, bl0, oacc, 0, 0, 0);
        oacc = __builtin_amdgcn_mfma_f32_16x16x32_bf16(al0, bh0, oacc, 0, 0, 0);
        oacc = __builtin_amdgcn_mfma_f32_16x16x32_bf16(ah1, bh1, oacc, 0, 0, 0);
        oacc = __builtin_amdgcn_mfma_f32_16x16x32_bf16(ah1, bl1, oacc, 0, 0, 0);
        oacc = __builtin_amdgcn_mfma_f32_16x16x32_bf16(al1, bh1, oacc, 0, 0, 0);
        if (ncol < OF) {
            float bias = bosL[ncol];
            #pragma unroll
            for (int rg = 0; rg < 4; ++rg) {
                float s  = oacc[rg] + bias;
                float sg = 1.f / (1.f + __expf(-s));
                size_t row = (size_t)(rowo + rg);
                pred[row * OF + ncol] = sg;
                if constexpr (FIRST) x2w[row * F2 + ncol] = sg;
            }
        }
    }
}

} // namespace

extern "C" void kernel_launch(void* const* d_in, const int* in_sizes, int n_in,
                              void* d_out, int out_size, void* d_ws, size_t ws_size,
                              hipStream_t stream) {
    const float* spec = (const float*)d_in[0];
    const float* Wq1  = (const float*)d_in[1];
    const float* Wk1  = (const float*)d_in[2];
    const float* Wv1  = (const float*)d_in[3];
    const float* rel1 = (const float*)d_in[4];
    const float* ln1g = (const float*)d_in[5];
    const float* ln1b = (const float*)d_in[6];
    const float* Wo   = (const float*)d_in[7];
    const float* bo   = (const float*)d_in[8];
    const float* Wq2  = (const float*)d_in[9];
    const float* Wk2  = (const float*)d_in[10];
    const float* Wv2  = (const float*)d_in[11];
    const float* rel2 = (const float*)d_in[12];
    const float* ln2g = (const float*)d_in[13];
    const float* ln2b = (const float*)d_in[14];
    const float* Wf   = (const float*)d_in[15];
    const float* bf_  = (const float*)d_in[16];

    float* outf   = (float*)d_out;
    float* frame  = outf;
    float* onset  = outf + (size_t)NROW * OF;
    float* attn_a = outf + (size_t)2 * NROW * OF;

    float* wsf = (float*)d_ws;
    float* q1 = wsf;
    float* k1 = q1 + (size_t)NROW * MC;
    float* v1 = k1 + (size_t)NROW * MC;
    float* x2 = v1 + (size_t)NROW * MC;                 // [NROW][136]
    unsigned short* wbuf1 = (unsigned short*)(x2 + (size_t)NROW * F2);
    unsigned short* wbuf2 = wbuf1 + (size_t)8 * 9216;
    unsigned short* woP1  = wbuf2 + (size_t)5 * 9216;   // [2][96][64]
    unsigned short* woP2  = woP1 + 2 * 6144;

    wprep_kernel<<<(144 * 8 * 32 + 255) / 256, 256, 0, stream>>>(Wq1, Wk1, Wv1, F1, 8, wbuf1);
    wprep_kernel<<<(144 * 5 * 32 + 255) / 256, 256, 0, stream>>>(Wq2, Wk2, Wv2, F2, 5, wbuf2);
    woprep_kernel<<<24, 256, 0, stream>>>(Wo, woP1);
    woprep_kernel<<<24, 256, 0, stream>>>(Wf, woP2);

    // phase 1
    proj_mfma<F1, 8><<<NROW / 64, 256, 0, stream>>>(spec, wbuf1, q1, k1, v1);
    attn_core<true><<<NROW / 64, 512, 0, stream>>>(q1, k1, v1, rel1, ln1g, ln1b,
                                                   attn_a, x2);
    pred_gemm<true><<<NROW / 64, 256, 0, stream>>>(x2, woP1, bo, onset, x2);
    // phase 2 (x2 cols 88..135 reused as y scratch)
    proj_mfma<F2, 5><<<NROW / 64, 256, 0, stream>>>(x2, wbuf2, q1, k1, v1);
    attn_core<false><<<NROW / 64, 512, 0, stream>>>(q1, k1, v1, rel2, ln2g, ln2b,
                                                    nullptr, x2);
    pred_gemm<false><<<NROW / 64, 256, 0, stream>>>(x2, woP2, bf_, frame, nullptr);
}